// Round 1
// baseline (166.414 us; speedup 1.0000x reference)
//
#include <hip/hip_runtime.h>

// CTC loss (blank=0, mean reduction, zero_infinity) for
// B=64, T=1024, K=512, L=100  ->  S = 2L+1 = 201 extended states.
//
// Three kernels:
//  1) k_probs: per (b,t) row: stable softmax over K=512, gather blank +
//     100 target classes, emit LINEAR probabilities pre-scaled by C=512.
//     Layout per row (104 floats): [0]=q_blank, [1]=0, [2+l]=q_label_l
//     (l=0..99), [102..103]=0 (padding -> probability-0 states).
//  2) k_ctc: forward recursion in linear domain, one wave per batch,
//     lane i holds states 4i..4i+3; exact power-of-2 rescale every 8
//     steps with integer exponent accumulation.
//  3) k_mean: mean over the 64 per-batch losses.

#define TT 1024
#define BB 64
#define KK 512
#define LL 100
#define ROW 104   // 0:blank, 1:pad, 2..101:labels, 102..103:pad

static constexpr float L2E = 1.44269504088896340736f;
static constexpr float LN2 = 0.69314718055994530942f;

__global__ __launch_bounds__(256) void k_probs(const float* __restrict__ logits,
                                               const int* __restrict__ targets,
                                               float* __restrict__ glp) {
  const int row = blockIdx.x;           // row = b*T + t
  const int b = row >> 10;              // T = 1024
  const float* x = logits + (size_t)row * KK;
  __shared__ float sx[KK];
  __shared__ float red[8];
  const int tid = threadIdx.x;

  float2 v = reinterpret_cast<const float2*>(x)[tid];   // 256 thr x 2 floats
  reinterpret_cast<float2*>(sx)[tid] = v;

  // block max
  float m = fmaxf(v.x, v.y);
  #pragma unroll
  for (int d = 1; d < 64; d <<= 1) m = fmaxf(m, __shfl_xor(m, d));
  const int wv = tid >> 6;
  if ((tid & 63) == 0) red[wv] = m;
  __syncthreads();
  m = fmaxf(fmaxf(red[0], red[1]), fmaxf(red[2], red[3]));

  // block sum of exp(x - m)
  float e = exp2f((v.x - m) * L2E) + exp2f((v.y - m) * L2E);
  #pragma unroll
  for (int d = 1; d < 64; d <<= 1) e += __shfl_xor(e, d);
  if ((tid & 63) == 0) red[4 + wv] = e;
  __syncthreads();
  const float tot = (red[4] + red[5]) + (red[6] + red[7]);
  const float inv = 512.0f / tot;       // fold C = 512 prescale (q = C*p)

  float* out = glp + (size_t)row * ROW;
  if (tid < ROW) {
    float p = 0.0f;
    if (tid == 0) {
      p = exp2f((sx[0] - m) * L2E) * inv;                 // blank (class 0)
    } else if (tid >= 2 && tid < 2 + LL) {
      const int c = targets[b * LL + (tid - 2)];          // c in [1, 512)
      p = exp2f((sx[c] - m) * L2E) * inv;
    }
    out[tid] = p;                                         // pads -> 0
  }
}

__global__ __launch_bounds__(64) void k_ctc(const float* __restrict__ glp,
                                            const int* __restrict__ targets,
                                            float* __restrict__ per) {
  const int b = blockIdx.x;
  const int i = threadIdx.x;            // lane, owns states 4i..4i+3
  const float* base = glp + (size_t)b * TT * ROW;
  const int* tg = targets + b * LL;

  // fixed per-lane label-prob offset: labels 2i and 2i+1 live at row
  // indices 2+2i, 3+2i (8B aligned float2). Lanes >= 50 clamp into pads.
  int offlab = 2 + 2 * i;
  if (offlab > 102) offlab = 102;

  // skip masks: state 4i+1 (label 2i) skips from 4i-1 iff tg[2i]!=tg[2i-1]
  //             state 4i+3 (label 2i+1) skips from 4i+1 iff tg[2i+1]!=tg[2i]
  const int l0 = 2 * i, l1 = 2 * i + 1;
  float mA = 0.0f, mB = 0.0f;
  if (i > 0 && l0 <= LL - 1) mA = (tg[l0] != tg[l0 - 1]) ? 1.0f : 0.0f;
  if (l1 <= LL - 1)          mB = (tg[l1] != tg[l1 - 1]) ? 1.0f : 0.0f;

  // t = 0 init: alpha[0] = q_blank(0), alpha[1] = q_label0(0), rest 0
  const float pb0 = base[0];
  const float2 pl0 = *reinterpret_cast<const float2*>(base + offlab);
  float a0 = (i == 0) ? pb0 : 0.0f;
  float a1 = (i == 0) ? pl0.x : 0.0f;
  float a2 = 0.0f, a3 = 0.0f;

  int eacc = 0;
  int t = 1;
  // main loop: chunks of 8 steps; loads issued 8-deep ahead of compute
  for (; t + 7 < TT; t += 8) {
    float pbv[8]; float2 plv[8];
    #pragma unroll
    for (int j = 0; j < 8; ++j) {
      const float* row = base + (t + j) * ROW;
      pbv[j] = row[0];                                     // uniform
      plv[j] = *reinterpret_cast<const float2*>(row + offlab);  // coalesced
    }
    #pragma unroll
    for (int j = 0; j < 8; ++j) {
      float prev = __shfl_up(a3, 1);          // alpha[4i-1] from lane i-1
      if (i == 0) prev = 0.0f;
      const float n0 = (a0 + prev) * pbv[j];               // s=4i   (blank)
      const float n1 = (a0 + a1 + mA * prev) * plv[j].x;   // s=4i+1 (label 2i)
      const float n2 = (a1 + a2) * pbv[j];                 // s=4i+2 (blank)
      const float n3 = (a2 + a3 + mB * a1) * plv[j].y;     // s=4i+3 (label 2i+1)
      a0 = n0; a1 = n1; a2 = n2; a3 = n3;
    }
    // exact power-of-2 rescale once per chunk (uniform across wave)
    float m = fmaxf(fmaxf(a0, a1), fmaxf(a2, a3));
    #pragma unroll
    for (int d = 1; d < 64; d <<= 1) m = fmaxf(m, __shfl_xor(m, d));
    if (m > 0.0f) {
      const int E = (int)((__float_as_uint(m) >> 23) & 255) - 127;
      const float scale = __uint_as_float((unsigned)(127 - E) << 23);
      a0 *= scale; a1 *= scale; a2 *= scale; a3 *= scale;
      eacc += E;
    }
  }
  // tail steps (7), no rescale needed
  for (; t < TT; ++t) {
    const float* row = base + t * ROW;
    const float pb = row[0];
    const float2 pl = *reinterpret_cast<const float2*>(row + offlab);
    float prev = __shfl_up(a3, 1);
    if (i == 0) prev = 0.0f;
    const float n0 = (a0 + prev) * pb;
    const float n1 = (a0 + a1 + mA * prev) * pl.x;
    const float n2 = (a1 + a2) * pb;
    const float n3 = (a2 + a3 + mB * a1) * pl.y;
    a0 = n0; a1 = n1; a2 = n2; a3 = n3;
  }

  // logl = logaddexp(alpha[200], alpha[199]); state 200 = lane50.a0,
  // state 199 = lane49.a3. True alpha = stored * 2^eacc / 512^1024.
  const float v199 = __shfl(a3, 49);
  const float v200 = __shfl(a0, 50);
  if (i == 0) {
    const float s = v199 + v200;
    float loss = 0.0f;                  // zero_infinity
    if (s > 0.0f) {
      const float logl = (log2f(s) + (float)(eacc - TT * 9)) * LN2; // 512 = 2^9
      loss = -logl / (float)LL;
    }
    per[b] = loss;
  }
}

__global__ __launch_bounds__(64) void k_mean(const float* __restrict__ per,
                                             float* __restrict__ out) {
  const int i = threadIdx.x;
  float v = per[i];
  #pragma unroll
  for (int d = 1; d < 64; d <<= 1) v += __shfl_xor(v, d);
  if (i == 0) out[0] = v * (1.0f / (float)BB);
}

extern "C" void kernel_launch(void* const* d_in, const int* in_sizes, int n_in,
                              void* d_out, int out_size, void* d_ws, size_t ws_size,
                              hipStream_t stream) {
  const float* logits = (const float*)d_in[0];   // (64, 1024, 512) f32
  const int* targets = (const int*)d_in[1];      // (64, 100) i32
  float* out = (float*)d_out;                    // scalar f32

  float* glp = (float*)d_ws;                                   // 64*1024*104 f32
  float* per = glp + (size_t)BB * TT * ROW;                    // 64 f32

  hipLaunchKernelGGL(k_probs, dim3(BB * TT), dim3(256), 0, stream,
                     logits, targets, glp);
  hipLaunchKernelGGL(k_ctc, dim3(BB), dim3(64), 0, stream,
                     glp, targets, per);
  hipLaunchKernelGGL(k_mean, dim3(1), dim3(64), 0, stream, per, out);
}

// Round 2
// 121.308 us; speedup vs baseline: 1.3718x; 1.3718x over previous
//
#include <hip/hip_runtime.h>

// CTC loss (blank=0, mean reduction, zero_infinity) for
// B=64, T=1024, K=512, L=100  ->  S = 2L+1 = 201 extended states.
//
//  1) k_probs: per (b,t) row: stable softmax over K=512 (one wave per row),
//     gather blank + 100 target classes, emit LINEAR probabilities
//     pre-scaled by C=512. Row layout (104 floats):
//     [0]=q_blank, [1]=0, [2+l]=q_label_l (l=0..99), [102..103]=0.
//  2) k_ctc: forward recursion in linear domain, one wave per batch,
//     lane i holds states 4i..4i+3. 16-step chunks, depth-2 register
//     prefetch, deferred power-of-2 rescale every 8 steps (exact int
//     exponent bookkeeping).
//  3) k_mean: mean over the 64 per-batch losses.

#define TT 1024
#define BB 64
#define KK 512
#define LL 100
#define ROW 104

static constexpr float L2E = 1.44269504088896340736f;
static constexpr float LN2 = 0.69314718055994530942f;

__global__ __launch_bounds__(256) void k_probs(const float* __restrict__ logits,
                                               const int* __restrict__ targets,
                                               float* __restrict__ glp) {
  const int wid = threadIdx.x >> 6;
  const int lane = threadIdx.x & 63;
  const int row = (blockIdx.x << 2) + wid;      // row = b*T + t
  const int b = row >> 10;                      // T = 1024
  const float* x = logits + (size_t)row * KK;

  __shared__ float sx[4][KK];

  const float4 v0 = reinterpret_cast<const float4*>(x)[lane];       // 4*lane
  const float4 v1 = reinterpret_cast<const float4*>(x)[lane + 64];  // 256+4*lane
  float4* sp = reinterpret_cast<float4*>(sx[wid]);
  sp[lane] = v0;
  sp[lane + 64] = v1;

  // wave max over 512
  float m = fmaxf(fmaxf(fmaxf(v0.x, v0.y), fmaxf(v0.z, v0.w)),
                  fmaxf(fmaxf(v1.x, v1.y), fmaxf(v1.z, v1.w)));
  #pragma unroll
  for (int d = 1; d < 64; d <<= 1) m = fmaxf(m, __shfl_xor(m, d));

  // wave sum of exp(x - m)
  float e = exp2f((v0.x - m) * L2E) + exp2f((v0.y - m) * L2E) +
            exp2f((v0.z - m) * L2E) + exp2f((v0.w - m) * L2E) +
            exp2f((v1.x - m) * L2E) + exp2f((v1.y - m) * L2E) +
            exp2f((v1.z - m) * L2E) + exp2f((v1.w - m) * L2E);
  #pragma unroll
  for (int d = 1; d < 64; d <<= 1) e += __shfl_xor(e, d);

  const float inv = 512.0f / e;                 // fold C = 512 prescale

  __syncthreads();                              // LDS row visible

  // gather: lane ln emits row entries 2ln, 2ln+1 (52 lanes cover 104)
  if (lane < 52) {
    float2 o = {0.0f, 0.0f};
    if (lane == 0) {
      o.x = exp2f((sx[wid][0] - m) * L2E) * inv;            // blank
    } else if (lane <= 50) {
      const int* tg = targets + b * LL + (2 * lane - 2);
      const int2 c = *reinterpret_cast<const int2*>(tg);
      o.x = exp2f((sx[wid][c.x] - m) * L2E) * inv;
      o.y = exp2f((sx[wid][c.y] - m) * L2E) * inv;
    }
    reinterpret_cast<float2*>(glp + (size_t)row * ROW)[lane] = o;
  }
}

__global__ __launch_bounds__(64) void k_ctc(const float* __restrict__ glp,
                                            const int* __restrict__ targets,
                                            float* __restrict__ per) {
  const int b = blockIdx.x;
  const int i = threadIdx.x;                    // lane, owns states 4i..4i+3
  const float* base = glp + (size_t)b * TT * ROW;
  const int* tg = targets + b * LL;

  int offlab = 2 + 2 * i;                       // float2 of label probs
  if (offlab > 102) offlab = 102;               // pad lanes -> zeros

  // skip masks
  const int l0 = 2 * i, l1 = 2 * i + 1;
  float mA = 0.0f, mB = 0.0f;
  if (i > 0 && l0 <= LL - 1) mA = (tg[l0] != tg[l0 - 1]) ? 1.0f : 0.0f;
  if (l1 <= LL - 1)          mB = (tg[l1] != tg[l1 - 1]) ? 1.0f : 0.0f;

  // virtual init: alpha_{-1} = delta at pre-state on lane 0; then 1024
  // uniform steps consume rows t = 0..1023 (64 chunks of 16).
  float a0 = (i == 0) ? 1.0f : 0.0f;
  float a1 = 0.0f, a2 = 0.0f, a3 = 0.0f;
  int eacc = 0;
  float mpend = 1.0f;                           // deferred-rescale max

  float pbA[16], pbB[16], pbC[16];
  float2 plA[16], plB[16], plC[16];

#define ISSUE(CB, PB, PL)                                                  \
  do {                                                                     \
    _Pragma("unroll") for (int j = 0; j < 16; ++j) {                       \
      const float* r_ = base + (size_t)((CB) * 16 + j) * ROW;              \
      PB[j] = r_[0];                                                       \
      PL[j] = *reinterpret_cast<const float2*>(r_ + offlab);               \
    }                                                                      \
  } while (0)

#define STEP(PBJ, PLJ)                                                     \
  do {                                                                     \
    float prev = __shfl_up(a3, 1);                                         \
    if (i == 0) prev = 0.0f;                                               \
    const float n0 = (a0 + prev) * (PBJ);                                  \
    const float n1 = (a0 + a1 + mA * prev) * (PLJ).x;                      \
    const float n2 = (a1 + a2) * (PBJ);                                    \
    const float n3 = (a2 + a3 + mB * a1) * (PLJ).y;                        \
    a0 = n0; a1 = n1; a2 = n2; a3 = n3;                                    \
  } while (0)

  // apply scale from the max computed 8 steps ago (deferred — its 6-shfl
  // butterfly latency overlaps the intervening recurrence steps), then
  // launch the next butterfly.
#define RESCALE()                                                          \
  do {                                                                     \
    if (mpend > 0.0f) {                                                    \
      const int E_ = (int)((__float_as_uint(mpend) >> 23) & 255) - 127;    \
      const float sc_ = __uint_as_float((unsigned)(127 - E_) << 23);       \
      a0 *= sc_; a1 *= sc_; a2 *= sc_; a3 *= sc_;                          \
      eacc += E_;                                                          \
    }                                                                      \
    float mm_ = fmaxf(fmaxf(a0, a1), fmaxf(a2, a3));                       \
    _Pragma("unroll") for (int d_ = 1; d_ < 64; d_ <<= 1)                  \
        mm_ = fmaxf(mm_, __shfl_xor(mm_, d_));                             \
    mpend = mm_;                                                           \
  } while (0)

#define CHUNK(PB, PL, PFC, PFPB, PFPL)                                     \
  do {                                                                     \
    if ((PFC) < 64) ISSUE(PFC, PFPB, PFPL);                                \
    _Pragma("unroll") for (int j = 0; j < 8; ++j) STEP(PB[j], PL[j]);      \
    RESCALE();                                                             \
    _Pragma("unroll") for (int j = 8; j < 16; ++j) STEP(PB[j], PL[j]);     \
    RESCALE();                                                             \
  } while (0)

  ISSUE(0, pbA, plA);
  ISSUE(1, pbB, plB);
  for (int c = 0; c < 63; c += 3) {
    CHUNK(pbA, plA, c + 2, pbC, plC);
    CHUNK(pbB, plB, c + 3, pbA, plA);
    CHUNK(pbC, plC, c + 4, pbB, plB);
  }
  // chunk 63 lives in buffer A (prefetched at c = 60)
  {
    _Pragma("unroll") for (int j = 0; j < 8; ++j) STEP(pbA[j], plA[j]);
    RESCALE();
    _Pragma("unroll") for (int j = 8; j < 16; ++j) STEP(pbA[j], plA[j]);
  }

  // logl = log(alpha[199] + alpha[200]); 199 = lane49.a3, 200 = lane50.a0.
  const float v199 = __shfl(a3, 49);
  const float v200 = __shfl(a0, 50);
  if (i == 0) {
    const float s = v199 + v200;
    float loss = 0.0f;                          // zero_infinity
    if (s > 0.0f) {
      const float logl = (log2f(s) + (float)(eacc - TT * 9)) * LN2;  // 512=2^9
      loss = -logl / (float)LL;
    }
    per[b] = loss;
  }
#undef ISSUE
#undef STEP
#undef RESCALE
#undef CHUNK
}

__global__ __launch_bounds__(64) void k_mean(const float* __restrict__ per,
                                             float* __restrict__ out) {
  const int i = threadIdx.x;
  float v = per[i];
  #pragma unroll
  for (int d = 1; d < 64; d <<= 1) v += __shfl_xor(v, d);
  if (i == 0) out[0] = v * (1.0f / (float)BB);
}

extern "C" void kernel_launch(void* const* d_in, const int* in_sizes, int n_in,
                              void* d_out, int out_size, void* d_ws, size_t ws_size,
                              hipStream_t stream) {
  const float* logits = (const float*)d_in[0];   // (64, 1024, 512) f32
  const int* targets = (const int*)d_in[1];      // (64, 100) i32
  float* out = (float*)d_out;                    // scalar f32

  float* glp = (float*)d_ws;                     // 64*1024*104 f32
  float* per = glp + (size_t)BB * TT * ROW;      // 64 f32

  hipLaunchKernelGGL(k_probs, dim3(BB * TT / 4), dim3(256), 0, stream,
                     logits, targets, glp);
  hipLaunchKernelGGL(k_ctc, dim3(BB), dim3(64), 0, stream,
                     glp, targets, per);
  hipLaunchKernelGGL(k_mean, dim3(1), dim3(64), 0, stream, per, out);
}

// Round 3
// 108.464 us; speedup vs baseline: 1.5343x; 1.1184x over previous
//
#include <hip/hip_runtime.h>

// CTC loss (blank=0, mean reduction, zero_infinity) for
// B=64, T=1024, K=512, L=100  ->  S = 2L+1 = 201 extended states.
//
//  1) k_probs: per (b,t) row: stable softmax over K=512 (one wave per row),
//     gather blank + 100 target classes, emit LINEAR probabilities
//     pre-scaled by C=512. Row layout (104 floats):
//     [0]=q_blank, [1]=0, [2+l]=q_label_l (l=0..99), [102..103]=0.
//  2) k_ctc: forward recursion in linear domain. 256-thread blocks:
//     wave 0 = consumer (recursion, reads LDS only); waves 1-3 = producers
//     staging 16-row chunks global->reg->LDS (double-buffered reg sets,
//     2-chunk slack, 4 LDS buffers, 1 barrier/chunk). Consumer does TWO
//     recursion steps per cross-lane exchange (one shfl batch of a1,a2,a3;
//     neighbor's new a3 recomputed locally from LDS prob). Exact power-of-2
//     rescale every 8 steps, deferred butterfly.
//  3) k_mean: mean over the 64 per-batch losses.

#define TT 1024
#define BB 64
#define KK 512
#define LL 100
#define ROW 104
#define CH 16                 // rows per chunk
#define NCH 64                // chunks (TT/CH)
#define CHF (CH * ROW)        // 1664 floats per chunk
#define CH4 (CHF / 4)         // 416 float4 per chunk

static constexpr float L2E = 1.44269504088896340736f;
static constexpr float LN2 = 0.69314718055994530942f;

__global__ __launch_bounds__(256) void k_probs(const float* __restrict__ logits,
                                               const int* __restrict__ targets,
                                               float* __restrict__ glp) {
  const int wid = threadIdx.x >> 6;
  const int lane = threadIdx.x & 63;
  const int row = (blockIdx.x << 2) + wid;      // row = b*T + t
  const int b = row >> 10;                      // T = 1024
  const float* x = logits + (size_t)row * KK;

  __shared__ float sx[4][KK];

  const float4 v0 = reinterpret_cast<const float4*>(x)[lane];
  const float4 v1 = reinterpret_cast<const float4*>(x)[lane + 64];
  float4* sp = reinterpret_cast<float4*>(sx[wid]);
  sp[lane] = v0;
  sp[lane + 64] = v1;

  float m = fmaxf(fmaxf(fmaxf(v0.x, v0.y), fmaxf(v0.z, v0.w)),
                  fmaxf(fmaxf(v1.x, v1.y), fmaxf(v1.z, v1.w)));
  #pragma unroll
  for (int d = 1; d < 64; d <<= 1) m = fmaxf(m, __shfl_xor(m, d));

  float e = exp2f((v0.x - m) * L2E) + exp2f((v0.y - m) * L2E) +
            exp2f((v0.z - m) * L2E) + exp2f((v0.w - m) * L2E) +
            exp2f((v1.x - m) * L2E) + exp2f((v1.y - m) * L2E) +
            exp2f((v1.z - m) * L2E) + exp2f((v1.w - m) * L2E);
  #pragma unroll
  for (int d = 1; d < 64; d <<= 1) e += __shfl_xor(e, d);

  const float inv = 512.0f / e;                 // fold C = 512 prescale

  __syncthreads();

  if (lane < 52) {
    float2 o = {0.0f, 0.0f};
    if (lane == 0) {
      o.x = exp2f((sx[wid][0] - m) * L2E) * inv;            // blank
    } else if (lane <= 50) {
      const int* tg = targets + b * LL + (2 * lane - 2);
      const int2 c = *reinterpret_cast<const int2*>(tg);
      o.x = exp2f((sx[wid][c.x] - m) * L2E) * inv;
      o.y = exp2f((sx[wid][c.y] - m) * L2E) * inv;
    }
    reinterpret_cast<float2*>(glp + (size_t)row * ROW)[lane] = o;
  }
}

__global__ __launch_bounds__(256) void k_ctc(const float* __restrict__ glp,
                                             const int* __restrict__ targets,
                                             float* __restrict__ per) {
  const int b = blockIdx.x;
  const int tid = threadIdx.x;
  const float* base = glp + (size_t)b * TT * ROW;

  __shared__ float lds[4][CHF];                 // 4 x 6656 B = 26.6 KB

  if (tid >= 64) {
    // ---------------- producers: waves 1-3 (192 threads) ----------------
    const int pt = tid - 64;                    // 0..191
    const float4* g = reinterpret_cast<const float4*>(base);
    float4 sA0, sA1, sA2, sB0, sB1, sB2;

#define P_ISSUE(S0, S1, S2, CHN)                                           \
    do { const float4* gc_ = g + (CHN) * CH4;                              \
         S0 = gc_[pt]; S1 = gc_[pt + 192];                                 \
         if (pt < 32) S2 = gc_[pt + 384]; } while (0)
#define P_WRITE(S0, S1, S2, CHN)                                           \
    do { float4* l_ = reinterpret_cast<float4*>(lds[(CHN) & 3]);           \
         l_[pt] = S0; l_[pt + 192] = S1;                                   \
         if (pt < 32) l_[pt + 384] = S2; } while (0)

    // prologue: ch1 -> B (odd), ch2 -> A (even); ch0 copied directly
    P_ISSUE(sB0, sB1, sB2, 1);
    P_ISSUE(sA0, sA1, sA2, 2);
    { float4 t0, t1, t2;
      P_ISSUE(t0, t1, t2, 0);
      P_WRITE(t0, t1, t2, 0); }
    __syncthreads();
    for (int c = 0; c < NCH; ++c) {
      const int w = c + 1;                      // chunk to write this iter
      if (w < NCH) {
        if (w & 1) P_WRITE(sB0, sB1, sB2, w);
        else       P_WRITE(sA0, sA1, sA2, w);
      }
      const int f = c + 3;                      // chunk to issue this iter
      if (f < NCH) {
        if (f & 1) P_ISSUE(sB0, sB1, sB2, f);
        else       P_ISSUE(sA0, sA1, sA2, f);
      }
      __syncthreads();
    }
#undef P_ISSUE
#undef P_WRITE
    return;
  }

  // ------------------- consumer: wave 0 (recursion) ---------------------
  const int i = tid;                            // lane, states 4i..4i+3
  const int* tg = targets + b * LL;

  int offlab = 2 + 2 * i;                       // label-prob float2 offset
  if (offlab > 102) offlab = 102;               // pad lanes -> zeros
  const int offp = offlab - 1;                  // neighbor's ply (0 for i=0)

  const int l0 = 2 * i, l1 = 2 * i + 1;
  float mA = 0.0f, mB = 0.0f;
  if (i > 0 && l0 <= LL - 1) mA = (tg[l0] != tg[l0 - 1]) ? 1.0f : 0.0f;
  if (l1 <= LL - 1)          mB = (tg[l1] != tg[l1 - 1]) ? 1.0f : 0.0f;
  float mBp = __shfl_up(mB, 1);                 // neighbor's mB
  if (i == 0) mBp = 0.0f;

  // virtual init: alpha_{-1} = delta on lane 0; 1024 uniform steps follow.
  float a0 = (i == 0) ? 1.0f : 0.0f;
  float a1 = 0.0f, a2 = 0.0f, a3 = 0.0f;
  int eacc = 0;
  float mpend = 1.0f;

#define RESCALE()                                                          \
  do {                                                                     \
    if (mpend > 0.0f) {                                                    \
      const int E_ = (int)((__float_as_uint(mpend) >> 23) & 255) - 127;    \
      const float sc_ = __uint_as_float((unsigned)(127 - E_) << 23);       \
      a0 *= sc_; a1 *= sc_; a2 *= sc_; a3 *= sc_;                          \
      eacc += E_;                                                          \
    }                                                                      \
    float mm_ = fmaxf(fmaxf(a0, a1), fmaxf(a2, a3));                       \
    _Pragma("unroll") for (int d_ = 1; d_ < 64; d_ <<= 1)                  \
        mm_ = fmaxf(mm_, __shfl_xor(mm_, d_));                             \
    mpend = mm_;                                                           \
  } while (0)

  __syncthreads();                              // matches producer prologue
  for (int c = 0; c < NCH; ++c) {
    const float* L = lds[c & 3];
    #pragma unroll
    for (int pr = 0; pr < 8; ++pr) {            // 2 recursion steps / pair
      const float* r0 = L + (2 * pr) * ROW;
      const float* r1 = r0 + ROW;
      const float PB = r0[0];
      const float2 PL = *reinterpret_cast<const float2*>(r0 + offlab);
      const float PYp = r0[offp];               // neighbor's ply, step t
      const float QB = r1[0];
      const float2 QL = *reinterpret_cast<const float2*>(r1 + offlab);

      float A1 = __shfl_up(a1, 1);
      float A2 = __shfl_up(a2, 1);
      float A3 = __shfl_up(a3, 1);
      if (i == 0) A3 = 0.0f;                    // A1,A2 are killed by PYp=0

      // step t
      const float b0 = (a0 + A3) * PB;
      const float b1 = (a0 + a1 + mA * A3) * PL.x;
      const float b2 = (a1 + a2) * PB;
      const float b3 = (a2 + a3 + mB * a1) * PL.y;
      const float b3p = (A2 + A3 + mBp * A1) * PYp;  // neighbor's new a3
      // step t+1
      a0 = (b0 + b3p) * QB;
      a1 = (b0 + b1 + mA * b3p) * QL.x;
      a2 = (b1 + b2) * QB;
      a3 = (b2 + b3 + mB * b1) * QL.y;

      if (pr == 3 || pr == 7) RESCALE();
    }
    __syncthreads();
  }
#undef RESCALE

  // logl = log(alpha[199] + alpha[200]); 199 = lane49.a3, 200 = lane50.a0.
  const float v199 = __shfl(a3, 49);
  const float v200 = __shfl(a0, 50);
  if (i == 0) {
    const float s = v199 + v200;
    float loss = 0.0f;                          // zero_infinity
    if (s > 0.0f) {
      const float logl = (log2f(s) + (float)(eacc - TT * 9)) * LN2; // 512=2^9
      loss = -logl / (float)LL;
    }
    per[b] = loss;
  }
}

__global__ __launch_bounds__(64) void k_mean(const float* __restrict__ per,
                                             float* __restrict__ out) {
  const int i = threadIdx.x;
  float v = per[i];
  #pragma unroll
  for (int d = 1; d < 64; d <<= 1) v += __shfl_xor(v, d);
  if (i == 0) out[0] = v * (1.0f / (float)BB);
}

extern "C" void kernel_launch(void* const* d_in, const int* in_sizes, int n_in,
                              void* d_out, int out_size, void* d_ws, size_t ws_size,
                              hipStream_t stream) {
  const float* logits = (const float*)d_in[0];   // (64, 1024, 512) f32
  const int* targets = (const int*)d_in[1];      // (64, 100) i32
  float* out = (float*)d_out;                    // scalar f32

  float* glp = (float*)d_ws;                     // 64*1024*104 f32
  float* per = glp + (size_t)BB * TT * ROW;      // 64 f32

  hipLaunchKernelGGL(k_probs, dim3(BB * TT / 4), dim3(256), 0, stream,
                     logits, targets, glp);
  hipLaunchKernelGGL(k_ctc, dim3(BB), dim3(256), 0, stream,
                     glp, targets, per);
  hipLaunchKernelGGL(k_mean, dim3(1), dim3(64), 0, stream, per, out);
}

// Round 4
// 85.820 us; speedup vs baseline: 1.9391x; 1.2639x over previous
//
#include <hip/hip_runtime.h>

// CTC loss (blank=0, mean reduction, zero_infinity) for
// B=64, T=1024, K=512, L=100  ->  S = 2L+1 = 201 extended states.
//
//  1) k_probs: per (b,t) row softmax over K=512 (one wave per row), gather
//     blank + 100 target classes, emit LINEAR probs pre-scaled by C=512.
//     Row layout (104 floats): [0]=blank, [1]=0, [2+l]=label_l, [102..103]=0.
//  2) k_ctc: linear-domain forward recursion. 256-thread blocks: wave 0 =
//     consumer (recursion, LDS-only reads); waves 1-3 = producers staging
//     16-row chunks global->reg->LDS (2-chunk slack, 4 LDS buffers, one
//     barrier per chunk). ALL cross-lane traffic on the consumer chain uses
//     DPP (VALU) — wave_shr:1 for the lane shift, row_shr/row_bcast for the
//     rescale max-reduce — keeping the in-order DS queue free of
//     chain-coupled ops (round-3 lesson: ds_bpermute butterflies serialize
//     into the DS queue and land back on the critical path).
//     Exact power-of-2 rescale every 8 steps, apply deferred by 8 steps.
//  3) k_mean: mean over the 64 per-batch losses.

#define TT 1024
#define BB 64
#define KK 512
#define LL 100
#define ROW 104
#define CH 16                 // rows per chunk
#define NCH 64                // chunks (TT/CH)
#define CHF (CH * ROW)        // 1664 floats per chunk
#define CH4 (CHF / 4)         // 416 float4 per chunk

static constexpr float L2E = 1.44269504088896340736f;
static constexpr float LN2 = 0.69314718055994530942f;

// lane i <- lane i-1, lane 0 <- 0.0f  (v_mov_b32_dpp wave_shr:1, VALU pipe)
__device__ __forceinline__ float dpp_shr1_z(float x) {
  return __builtin_bit_cast(float,
      __builtin_amdgcn_update_dpp(0, __builtin_bit_cast(int, x),
                                  0x138, 0xf, 0xf, true));
}

// wave64 max via DPP (row_shr 1/2/4/8 + row_bcast15/31), broadcast with
// v_readlane (SALU). No DS-queue involvement. Valid for x >= 0 (0-fill).
__device__ __forceinline__ float wave_max_dpp(float v) {
#define DPPMAX(C)                                                          \
  v = fmaxf(v, __builtin_bit_cast(float, __builtin_amdgcn_update_dpp(      \
                   0, __builtin_bit_cast(int, v), C, 0xf, 0xf, true)))
  DPPMAX(0x111); DPPMAX(0x112); DPPMAX(0x114); DPPMAX(0x118);  // row_shr
  DPPMAX(0x142); DPPMAX(0x143);                                // bcast15/31
#undef DPPMAX
  return __builtin_bit_cast(float,
      __builtin_amdgcn_readlane(__builtin_bit_cast(int, v), 63));
}

__global__ __launch_bounds__(256) void k_probs(const float* __restrict__ logits,
                                               const int* __restrict__ targets,
                                               float* __restrict__ glp) {
  const int wid = threadIdx.x >> 6;
  const int lane = threadIdx.x & 63;
  const int row = (blockIdx.x << 2) + wid;      // row = b*T + t
  const int b = row >> 10;                      // T = 1024
  const float* x = logits + (size_t)row * KK;

  __shared__ float sx[4][KK];

  const float4 v0 = reinterpret_cast<const float4*>(x)[lane];
  const float4 v1 = reinterpret_cast<const float4*>(x)[lane + 64];
  float4* sp = reinterpret_cast<float4*>(sx[wid]);
  sp[lane] = v0;
  sp[lane + 64] = v1;

  float m = fmaxf(fmaxf(fmaxf(v0.x, v0.y), fmaxf(v0.z, v0.w)),
                  fmaxf(fmaxf(v1.x, v1.y), fmaxf(v1.z, v1.w)));
  #pragma unroll
  for (int d = 1; d < 64; d <<= 1) m = fmaxf(m, __shfl_xor(m, d));

  float e = exp2f((v0.x - m) * L2E) + exp2f((v0.y - m) * L2E) +
            exp2f((v0.z - m) * L2E) + exp2f((v0.w - m) * L2E) +
            exp2f((v1.x - m) * L2E) + exp2f((v1.y - m) * L2E) +
            exp2f((v1.z - m) * L2E) + exp2f((v1.w - m) * L2E);
  #pragma unroll
  for (int d = 1; d < 64; d <<= 1) e += __shfl_xor(e, d);

  const float inv = 512.0f / e;                 // fold C = 512 prescale

  __syncthreads();

  if (lane < 52) {
    float2 o = {0.0f, 0.0f};
    if (lane == 0) {
      o.x = exp2f((sx[wid][0] - m) * L2E) * inv;            // blank
    } else if (lane <= 50) {
      const int* tg = targets + b * LL + (2 * lane - 2);
      const int2 c = *reinterpret_cast<const int2*>(tg);
      o.x = exp2f((sx[wid][c.x] - m) * L2E) * inv;
      o.y = exp2f((sx[wid][c.y] - m) * L2E) * inv;
    }
    reinterpret_cast<float2*>(glp + (size_t)row * ROW)[lane] = o;
  }
}

__global__ __launch_bounds__(256) void k_ctc(const float* __restrict__ glp,
                                             const int* __restrict__ targets,
                                             float* __restrict__ per) {
  const int b = blockIdx.x;
  const int tid = threadIdx.x;
  const float* base = glp + (size_t)b * TT * ROW;

  __shared__ float lds[4][CHF];                 // 4 x 6656 B = 26.6 KB

  if (tid >= 64) {
    // ---------------- producers: waves 1-3 (192 threads) ----------------
    const int pt = tid - 64;                    // 0..191
    const float4* g = reinterpret_cast<const float4*>(base);
    float4 sA0, sA1, sA2, sB0, sB1, sB2;

#define P_ISSUE(S0, S1, S2, CHN)                                           \
    do { const float4* gc_ = g + (CHN) * CH4;                              \
         S0 = gc_[pt]; S1 = gc_[pt + 192];                                 \
         if (pt < 32) S2 = gc_[pt + 384]; } while (0)
#define P_WRITE(S0, S1, S2, CHN)                                           \
    do { float4* l_ = reinterpret_cast<float4*>(lds[(CHN) & 3]);           \
         l_[pt] = S0; l_[pt + 192] = S1;                                   \
         if (pt < 32) l_[pt + 384] = S2; } while (0)

    P_ISSUE(sB0, sB1, sB2, 1);
    P_ISSUE(sA0, sA1, sA2, 2);
    { float4 t0, t1, t2;
      P_ISSUE(t0, t1, t2, 0);
      P_WRITE(t0, t1, t2, 0); }
    __syncthreads();
    for (int c = 0; c < NCH; ++c) {
      const int w = c + 1;                      // chunk to write this iter
      if (w < NCH) {
        if (w & 1) P_WRITE(sB0, sB1, sB2, w);
        else       P_WRITE(sA0, sA1, sA2, w);
      }
      const int f = c + 3;                      // chunk to issue this iter
      if (f < NCH) {
        if (f & 1) P_ISSUE(sB0, sB1, sB2, f);
        else       P_ISSUE(sA0, sA1, sA2, f);
      }
      __syncthreads();
    }
#undef P_ISSUE
#undef P_WRITE
    return;
  }

  // ------------------- consumer: wave 0 (recursion) ---------------------
  const int i = tid;                            // lane, states 4i..4i+3
  const int* tg = targets + b * LL;

  int offlab = 2 + 2 * i;                       // label-prob float2 offset
  if (offlab > 102) offlab = 102;               // pad lanes -> zeros

  const int l0 = 2 * i, l1 = 2 * i + 1;
  float mA = 0.0f, mB = 0.0f;
  if (i > 0 && l0 <= LL - 1) mA = (tg[l0] != tg[l0 - 1]) ? 1.0f : 0.0f;
  if (l1 <= LL - 1)          mB = (tg[l1] != tg[l1 - 1]) ? 1.0f : 0.0f;
  float mBp = __shfl_up(mB, 1);                 // neighbor's mB (init only)
  if (i == 0) mBp = 0.0f;

  // virtual init: alpha_{-1} = delta on lane 0; 1024 uniform steps follow.
  float a0 = (i == 0) ? 1.0f : 0.0f;
  float a1 = 0.0f, a2 = 0.0f, a3 = 0.0f;
  int eacc = 0;
  float mpend = 1.0f;                           // deferred-rescale max (uniform)

#define RESCALE()                                                          \
  do {                                                                     \
    if (mpend > 0.0f) {                                                    \
      const int E_ = (int)((__float_as_uint(mpend) >> 23) & 255) - 127;    \
      const float sc_ = __uint_as_float((unsigned)(127 - E_) << 23);       \
      a0 *= sc_; a1 *= sc_; a2 *= sc_; a3 *= sc_;                          \
      eacc += E_;                                                          \
    }                                                                      \
    mpend = wave_max_dpp(fmaxf(fmaxf(a0, a1), fmaxf(a2, a3)));             \
  } while (0)

  __syncthreads();                              // matches producer prologue
  for (int c = 0; c < NCH; ++c) {
    const float* L = lds[c & 3];
    #pragma unroll
    for (int pr = 0; pr < 8; ++pr) {            // 2 recursion steps / pair
      const float* r0 = L + (2 * pr) * ROW;
      const float PB = r0[0];
      const float2 PL = *reinterpret_cast<const float2*>(r0 + offlab);
      const float QB = r0[ROW];
      const float2 QL = *reinterpret_cast<const float2*>(r0 + ROW + offlab);

      const float A1 = dpp_shr1_z(a1);          // lane0 -> 0 (boundary)
      const float A2 = dpp_shr1_z(a2);
      const float A3 = dpp_shr1_z(a3);
      const float PYp = dpp_shr1_z(PL.y);       // neighbor's label prob

      // step t
      const float b0 = (a0 + A3) * PB;
      const float b1 = (a0 + a1 + mA * A3) * PL.x;
      const float b2 = (a1 + a2) * PB;
      const float b3 = (a2 + a3 + mB * a1) * PL.y;
      const float b3p = (A2 + A3 + mBp * A1) * PYp;  // neighbor's new a3
      // step t+1
      a0 = (b0 + b3p) * QB;
      a1 = (b0 + b1 + mA * b3p) * QL.x;
      a2 = (b1 + b2) * QB;
      a3 = (b2 + b3 + mB * b1) * QL.y;

      if (pr == 3 || pr == 7) RESCALE();
    }
    __syncthreads();
  }
#undef RESCALE

  // logl = log(alpha[199] + alpha[200]); 199 = lane49.a3, 200 = lane50.a0.
  const float v199 = __shfl(a3, 49);
  const float v200 = __shfl(a0, 50);
  if (i == 0) {
    const float s = v199 + v200;
    float loss = 0.0f;                          // zero_infinity
    if (s > 0.0f) {
      const float logl = (log2f(s) + (float)(eacc - TT * 9)) * LN2; // 512=2^9
      loss = -logl / (float)LL;
    }
    per[b] = loss;
  }
}

__global__ __launch_bounds__(64) void k_mean(const float* __restrict__ per,
                                             float* __restrict__ out) {
  const int i = threadIdx.x;
  float v = per[i];
  #pragma unroll
  for (int d = 1; d < 64; d <<= 1) v += __shfl_xor(v, d);
  if (i == 0) out[0] = v * (1.0f / (float)BB);
}

extern "C" void kernel_launch(void* const* d_in, const int* in_sizes, int n_in,
                              void* d_out, int out_size, void* d_ws, size_t ws_size,
                              hipStream_t stream) {
  const float* logits = (const float*)d_in[0];   // (64, 1024, 512) f32
  const int* targets = (const int*)d_in[1];      // (64, 100) i32
  float* out = (float*)d_out;                    // scalar f32

  float* glp = (float*)d_ws;                     // 64*1024*104 f32
  float* per = glp + (size_t)BB * TT * ROW;      // 64 f32

  hipLaunchKernelGGL(k_probs, dim3(BB * TT / 4), dim3(256), 0, stream,
                     logits, targets, glp);
  hipLaunchKernelGGL(k_ctc, dim3(BB), dim3(256), 0, stream,
                     glp, targets, per);
  hipLaunchKernelGGL(k_mean, dim3(1), dim3(64), 0, stream, per, out);
}

// Round 5
// 80.067 us; speedup vs baseline: 2.0784x; 1.0718x over previous
//
#include <hip/hip_runtime.h>

// CTC loss (blank=0, mean reduction, zero_infinity) for
// B=64, T=1024, K=512, L=100  ->  S = 2L+1 = 201 extended states.
//
// Ratio formulation: factor prod_t p_blank(t) out of every alpha state.
// beta recursion:  even states: b' = (sums)          [no multiply]
//                  odd  states: b' = (sums) * r      [r = p_lab / p_blank]
// log-likelihood = log2(beta_end_sum) + eacc + sum_t lb(t) - T*9, in ln units
// where lb(t) = log2(512 * p_blank(t)) is emitted per (b,t) by k_probs.
//
//  1) k_probs: per (b,t) row (one wave each): ratios r = exp2((x_lab-x_blank)
//     *log2e) for the 100 targets -> glp row (104 floats: [0..1]=0,
//     [2+2p..]=ratio pairs, [102..103]=0); lb -> dense lbArr[b][t].
//  2) k_ctc: linear-domain forward recursion. 256-thread blocks: wave 0 =
//     consumer (recursion, LDS-only, all cross-lane via DPP); waves 1-3 =
//     producers staging 16-row chunks global->reg->LDS (2-chunk slack,
//     4 LDS buffers, 1 barrier/chunk). Chunk-top batched register load of
//     all 16 ratio float2s (one DS-latency exposure per chunk). Exact
//     power-of-2 rescale every 4 steps, apply deferred one window.
//  3) k_mean: mean over the 64 per-batch losses.

#define TT 1024
#define BB 64
#define KK 512
#define LL 100
#define ROW 104
#define CH 16                 // rows per chunk
#define NCH 64                // chunks (TT/CH)
#define CHF (CH * ROW)        // 1664 floats per chunk
#define CH4 (CHF / 4)         // 416 float4 per chunk

static constexpr float L2E = 1.44269504088896340736f;
static constexpr float LN2 = 0.69314718055994530942f;

// lane i <- lane i-1, lane 0 <- 0.0f  (v_mov_b32_dpp wave_shr:1, VALU pipe)
__device__ __forceinline__ float dpp_shr1_z(float x) {
  return __builtin_bit_cast(float,
      __builtin_amdgcn_update_dpp(0, __builtin_bit_cast(int, x),
                                  0x138, 0xf, 0xf, true));
}

// wave64 max via DPP (row_shr 1/2/4/8 + row_bcast15/31) + v_readlane.
// No DS-queue involvement. Valid for x >= 0 (0-fill).
__device__ __forceinline__ float wave_max_dpp(float v) {
#define DPPMAX(C)                                                          \
  v = fmaxf(v, __builtin_bit_cast(float, __builtin_amdgcn_update_dpp(      \
                   0, __builtin_bit_cast(int, v), C, 0xf, 0xf, true)))
  DPPMAX(0x111); DPPMAX(0x112); DPPMAX(0x114); DPPMAX(0x118);  // row_shr
  DPPMAX(0x142); DPPMAX(0x143);                                // bcast15/31
#undef DPPMAX
  return __builtin_bit_cast(float,
      __builtin_amdgcn_readlane(__builtin_bit_cast(int, v), 63));
}

__global__ __launch_bounds__(256) void k_probs(const float* __restrict__ logits,
                                               const int* __restrict__ targets,
                                               float* __restrict__ glp,
                                               float* __restrict__ lbArr) {
  const int wid = threadIdx.x >> 6;
  const int lane = threadIdx.x & 63;
  const int row = (blockIdx.x << 2) + wid;      // row = b*T + t
  const int b = row >> 10;                      // T = 1024
  const float* x = logits + (size_t)row * KK;

  __shared__ float sx[4][KK];

  const float4 v0 = reinterpret_cast<const float4*>(x)[lane];
  const float4 v1 = reinterpret_cast<const float4*>(x)[lane + 64];
  float4* sp = reinterpret_cast<float4*>(sx[wid]);
  sp[lane] = v0;
  sp[lane + 64] = v1;

  float m = fmaxf(fmaxf(fmaxf(v0.x, v0.y), fmaxf(v0.z, v0.w)),
                  fmaxf(fmaxf(v1.x, v1.y), fmaxf(v1.z, v1.w)));
  #pragma unroll
  for (int d = 1; d < 64; d <<= 1) m = fmaxf(m, __shfl_xor(m, d));

  float e = exp2f((v0.x - m) * L2E) + exp2f((v0.y - m) * L2E) +
            exp2f((v0.z - m) * L2E) + exp2f((v0.w - m) * L2E) +
            exp2f((v1.x - m) * L2E) + exp2f((v1.y - m) * L2E) +
            exp2f((v1.z - m) * L2E) + exp2f((v1.w - m) * L2E);
  #pragma unroll
  for (int d = 1; d < 64; d <<= 1) e += __shfl_xor(e, d);

  __syncthreads();
  const float xb = sx[wid][0];                  // blank logit

  if (lane < 52) {
    float2 o = {0.0f, 0.0f};
    if (lane >= 1 && lane <= 50) {
      const int* tg = targets + b * LL + (2 * lane - 2);
      const int2 c = *reinterpret_cast<const int2*>(tg);
      o.x = exp2f((sx[wid][c.x] - xb) * L2E);   // ratio p_lab / p_blank
      o.y = exp2f((sx[wid][c.y] - xb) * L2E);
    }
    reinterpret_cast<float2*>(glp + (size_t)row * ROW)[lane] = o;
  }
  // lb = log2(512 * p_blank) = (xb - m)*log2e + 9 - log2(sum exp)
  if (lane == 0) lbArr[row] = (xb - m) * L2E + 9.0f - log2f(e);
}

__global__ __launch_bounds__(256) void k_ctc(const float* __restrict__ glp,
                                             const float* __restrict__ lbArr,
                                             const int* __restrict__ targets,
                                             float* __restrict__ per) {
  const int b = blockIdx.x;
  const int tid = threadIdx.x;
  const float* base = glp + (size_t)b * TT * ROW;

  __shared__ float lds[4][CHF];                 // 4 x 6656 B = 26.6 KB

  if (tid >= 64) {
    // ---------------- producers: waves 1-3 (192 threads) ----------------
    const int pt = tid - 64;                    // 0..191
    const float4* g = reinterpret_cast<const float4*>(base);
    float4 sA0, sA1, sA2, sB0, sB1, sB2;

#define P_ISSUE(S0, S1, S2, CHN)                                           \
    do { const float4* gc_ = g + (CHN) * CH4;                              \
         S0 = gc_[pt]; S1 = gc_[pt + 192];                                 \
         if (pt < 32) S2 = gc_[pt + 384]; } while (0)
#define P_WRITE(S0, S1, S2, CHN)                                           \
    do { float4* l_ = reinterpret_cast<float4*>(lds[(CHN) & 3]);           \
         l_[pt] = S0; l_[pt + 192] = S1;                                   \
         if (pt < 32) l_[pt + 384] = S2; } while (0)

    P_ISSUE(sB0, sB1, sB2, 1);
    P_ISSUE(sA0, sA1, sA2, 2);
    { float4 t0, t1, t2;
      P_ISSUE(t0, t1, t2, 0);
      P_WRITE(t0, t1, t2, 0); }
    __syncthreads();
    for (int c = 0; c < NCH; ++c) {
      const int w = c + 1;                      // chunk to write this iter
      if (w < NCH) {
        if (w & 1) P_WRITE(sB0, sB1, sB2, w);
        else       P_WRITE(sA0, sA1, sA2, w);
      }
      const int f = c + 3;                      // chunk to issue this iter
      if (f < NCH) {
        if (f & 1) P_ISSUE(sB0, sB1, sB2, f);
        else       P_ISSUE(sA0, sA1, sA2, f);
      }
      __syncthreads();
    }
#undef P_ISSUE
#undef P_WRITE
    return;
  }

  // ------------------- consumer: wave 0 (recursion) ---------------------
  const int i = tid;                            // lane, states 4i..4i+3
  const int* tg = targets + b * LL;

  int offlab = 2 + 2 * i;                       // ratio float2 offset
  if (offlab > 102) offlab = 102;               // pad lanes -> zeros

  const int l0 = 2 * i, l1 = 2 * i + 1;
  float mA = 0.0f, mB = 0.0f;
  if (i > 0 && l0 <= LL - 1) mA = (tg[l0] != tg[l0 - 1]) ? 1.0f : 0.0f;
  if (l1 <= LL - 1)          mB = (tg[l1] != tg[l1 - 1]) ? 1.0f : 0.0f;
  float mBp = __shfl_up(mB, 1);                 // neighbor's mB (init only)
  if (i == 0) mBp = 0.0f;

  // virtual init: beta_{-1} = delta on lane 0; 1024 uniform steps follow.
  float a0 = (i == 0) ? 1.0f : 0.0f;
  float a1 = 0.0f, a2 = 0.0f, a3 = 0.0f;
  int eacc = 0;
  float mpend = 1.0f;                           // deferred-rescale max

#define RESCALE()                                                          \
  do {                                                                     \
    if (mpend > 0.0f) {                                                    \
      const int E_ = (int)((__float_as_uint(mpend) >> 23) & 255) - 127;    \
      const float sc_ = __uint_as_float((unsigned)(127 - E_) << 23);       \
      a0 *= sc_; a1 *= sc_; a2 *= sc_; a3 *= sc_;                          \
      eacc += E_;                                                          \
    }                                                                      \
    mpend = wave_max_dpp(fmaxf(fmaxf(a0, a1), fmaxf(a2, a3)));             \
  } while (0)

  __syncthreads();                              // matches producer prologue
  for (int c = 0; c < NCH; ++c) {
    const float* Lp = lds[c & 3] + offlab;
    float2 R[16];                               // chunk-top batched loads
    #pragma unroll
    for (int j = 0; j < 16; ++j)
      R[j] = *reinterpret_cast<const float2*>(Lp + j * ROW);
    #pragma unroll
    for (int pr = 0; pr < 8; ++pr) {            // 2 recursion steps / pair
      const float2 PL = R[2 * pr];
      const float2 QL = R[2 * pr + 1];

      const float A1 = dpp_shr1_z(a1);          // lane0 -> 0 (boundary)
      const float A2 = dpp_shr1_z(a2);
      const float A3 = dpp_shr1_z(a3);
      const float RYp = dpp_shr1_z(PL.y);       // neighbor's ratio

      // step t
      const float b0 = a0 + A3;                       // s=4i   (blank)
      const float b1 = (a0 + a1 + mA * A3) * PL.x;    // s=4i+1 (label 2i)
      const float b2 = a1 + a2;                       // s=4i+2 (blank)
      const float b3 = (a2 + a3 + mB * a1) * PL.y;    // s=4i+3 (label 2i+1)
      const float b3p = (A2 + A3 + mBp * A1) * RYp;   // neighbor's new a3
      // step t+1
      a0 = b0 + b3p;
      a1 = (b0 + b1 + mA * b3p) * QL.x;
      a2 = b1 + b2;
      a3 = (b2 + b3 + mB * b1) * QL.y;

      if (pr & 1) RESCALE();                    // every 4 steps
    }
    __syncthreads();
  }
#undef RESCALE

  // epilogue: sum lb over t (coalesced float4 reads), wave-reduce.
  float s4 = 0.0f;
  {
    const float4* lbv = reinterpret_cast<const float4*>(lbArr + (size_t)b * TT);
    #pragma unroll
    for (int j = 0; j < 4; ++j) {
      const float4 v = lbv[i + 64 * j];
      s4 += (v.x + v.y) + (v.z + v.w);
    }
    #pragma unroll
    for (int d = 1; d < 64; d <<= 1) s4 += __shfl_xor(s4, d);
  }

  // logl = log(beta[199] + beta[200]) + ...; 199 = lane49.a3, 200 = lane50.a0
  const float v199 = __shfl(a3, 49);
  const float v200 = __shfl(a0, 50);
  if (i == 0) {
    const float s = v199 + v200;
    float loss = 0.0f;                          // zero_infinity
    if (s > 0.0f) {
      const float logl2 = log2f(s) + (float)eacc + s4 - (float)(TT * 9);
      loss = -(logl2 * LN2) / (float)LL;
    }
    per[b] = loss;
  }
}

__global__ __launch_bounds__(64) void k_mean(const float* __restrict__ per,
                                             float* __restrict__ out) {
  const int i = threadIdx.x;
  float v = per[i];
  #pragma unroll
  for (int d = 1; d < 64; d <<= 1) v += __shfl_xor(v, d);
  if (i == 0) out[0] = v * (1.0f / (float)BB);
}

extern "C" void kernel_launch(void* const* d_in, const int* in_sizes, int n_in,
                              void* d_out, int out_size, void* d_ws, size_t ws_size,
                              hipStream_t stream) {
  const float* logits = (const float*)d_in[0];   // (64, 1024, 512) f32
  const int* targets = (const int*)d_in[1];      // (64, 100) i32
  float* out = (float*)d_out;                    // scalar f32

  float* glp = (float*)d_ws;                     // 64*1024*104 f32
  float* lbArr = glp + (size_t)BB * TT * ROW;    // 64*1024 f32
  float* per = lbArr + (size_t)BB * TT;          // 64 f32

  hipLaunchKernelGGL(k_probs, dim3(BB * TT / 4), dim3(256), 0, stream,
                     logits, targets, glp, lbArr);
  hipLaunchKernelGGL(k_ctc, dim3(BB), dim3(256), 0, stream,
                     glp, lbArr, targets, per);
  hipLaunchKernelGGL(k_mean, dim3(1), dim3(64), 0, stream, per, out);
}